// Round 10
// baseline (24490.929 us; speedup 1.0000x reference)
//
#include <hip/hip_runtime.h>

#define LSEQ 2048
#define HID 512

// ws dword offsets
#define OFF_YT 0            // yT[2048][128] f32
#define OFF_H1 262144       // h1 ring u16[4 slot][8 bg][2 pl][64 k8][16 n][8 kk] = 1MB
#define OFF_H2 524288       // h2 ring, same
#define OFF_FLG 786432      // flags byte[2049][8 bg][32 j]
#define FLG_DWORDS 131136

// LDS byte offsets
#define TILE2 0             // 32KB: h2 tile (hi 16KB, lo 16KB)
#define TILE1 32768         // 32KB: h1 tile
#define PSUM  65536         // 4KB: ih2 partials [4 mt][64 lane] f32x4
#define BNC   69632         // 2KB: h2 512 u16 | h1 512 u16
#define OUTP  71680         // 1KB: 16x16 f32
#define LWL   72704         // 2KB: Wlin
#define LDSSZ 74752

typedef __attribute__((ext_vector_type(8))) short short8;
typedef __attribute__((ext_vector_type(4))) float f32x4;
typedef __attribute__((ext_vector_type(8))) unsigned short ushort8;

typedef __attribute__((address_space(1))) const unsigned int GU32;
typedef __attribute__((address_space(3))) unsigned int LU32;

__device__ __forceinline__ float sigm(float x){ return 1.0f/(1.0f + __expf(-x)); }
__device__ __forceinline__ float tanhf_fast(float x){
  float ax = fabsf(x);
  float e = __expf(2.0f*ax);
  float t = 1.0f - 2.0f/(e + 1.0f);
  return x < 0.0f ? -t : t;
}
__device__ __forceinline__ unsigned short f2bf(float x){
  unsigned u = __builtin_bit_cast(unsigned, x);
  u += 0x7fffu + ((u>>16)&1u);
  return (unsigned short)(u>>16);
}
__device__ __forceinline__ float bf2f(unsigned short h){
  unsigned u = ((unsigned)h)<<16;
  return __builtin_bit_cast(float, u);
}
__device__ __forceinline__ f32x4 mm(short8 a, short8 b, f32x4 c){
  return __builtin_amdgcn_mfma_f32_16x16x32_bf16(a, b, c, 0, 0, 0);
}

// ---- proven LLC-coherent dataflow primitives (r5-r8) ----
__device__ __forceinline__ void polld(unsigned* w){       // wait 4 byte-flags
  while (__hip_atomic_load(w, __ATOMIC_RELAXED, __HIP_MEMORY_SCOPE_AGENT) != 0x01010101u)
    __builtin_amdgcn_s_sleep(1);
}
__device__ __forceinline__ void setb(unsigned char* p){
  __hip_atomic_store(p, (unsigned char)1, __ATOMIC_RELAXED, __HIP_MEMORY_SCOPE_AGENT);
}
__device__ __forceinline__ void st128cc(unsigned short* p, ushort8 v){
  asm volatile("global_store_dwordx4 %0, %1, off sc0 sc1"
               :: "v"(p), "v"(v) : "memory");
}
#define DRAIN() asm volatile("s_waitcnt vmcnt(0)" ::: "memory")

// pack 16 A-fragments (hi & lo bf16): wave covers 4 units x 4 gates, full K (r8-proven)
__device__ __forceinline__ void apack(const float* __restrict__ W, int u_w, int l15, int hig,
                                      short8* whi, short8* wlo){
  const int m = l15;
  const int row = (m&3)*HID + u_w + (m>>2);
  const float* wp0 = W + row*HID + hig*8;
  #pragma unroll
  for (int kt = 0; kt < 16; ++kt){
    short8 h8, l8;
    #pragma unroll
    for (int j = 0; j < 8; ++j){
      float v = wp0[kt*32 + j];
      unsigned short hb = f2bf(v);
      h8[j] = (short)hb;
      l8[j] = (short)f2bf(v - bf2f(hb));
    }
    whi[kt] = h8; wlo[kt] = l8;
  }
}

// transpose y -> yT; zero h2 ring slot 3; zero flags (every launch)
__global__ void init_kernel(const float* __restrict__ y, float* __restrict__ ws){
  int idx = blockIdx.x*256 + threadIdx.x;
  if (idx < LSEQ*128){
    int t = idx >> 7, n = idx & 127;
    ws[OFF_YT + idx] = y[n*LSEQ + t];
  }
  if (idx < 65536) ((unsigned*)(ws + OFF_H2))[196608 + idx] = 0u;   // slot 3, all bg
  if (idx < FLG_DWORDS) ((unsigned*)(ws + OFF_FLG))[idx] = 0u;
}

__launch_bounds__(768)
__global__ void lstm_kernel(
    const float* __restrict__ yT,
    const float* __restrict__ Wih1, const float* __restrict__ Whh1,
    const float* __restrict__ bi1,  const float* __restrict__ bh1,
    const float* __restrict__ Wih2, const float* __restrict__ Whh2,
    const float* __restrict__ bi2,  const float* __restrict__ bh2,
    const float* __restrict__ Wlin, const float* __restrict__ blin,
    unsigned short* __restrict__ h1u, unsigned short* __restrict__ h2u,
    float* __restrict__ out, unsigned char* __restrict__ flg)
{
  __shared__ unsigned char smem[LDSSZ];
  unsigned short* bnc = (unsigned short*)(smem + BNC);
  float* lwl  = (float*)(smem + LWL);
  float* outp = (float*)(smem + OUTP);
  const int tid  = threadIdx.x;
  const int lane = tid & 63;
  const int wv   = __builtin_amdgcn_readfirstlane(tid >> 6);
  const int blk  = blockIdx.x;
  const int l15  = lane & 15, hig = lane >> 4;
  const int bg   = blk >> 5;          // batch group (16 batch)
  const int j32  = blk & 31;          // unit group (16 units)
  const int u0   = j32*16;
  const int g    = wv >> 2;           // 0=hh2, 1=ih2, 2=hh1
  const int mt   = wv & 3;            // M-subtile (4 units)
  const int u_w  = u0 + mt*4;
  const int ul   = mt*4 + hig;        // this lane's local unit (act phase)

  // weights: full K, r8-proven layout
  const float* Wsrc = (g==0) ? Whh2 : (g==1) ? Wih2 : Whh1;
  short8 whi[16], wlo[16];
  apack(Wsrc, u_w, l15, hig, whi, wlo);

  float bsum[4], wih[4], cst = 0.f;
  if (g == 0){
    #pragma unroll
    for (int j = 0; j < 4; ++j) bsum[j] = bi2[j*HID + u0 + ul] + bh2[j*HID + u0 + ul];
  } else if (g == 2){
    #pragma unroll
    for (int j = 0; j < 4; ++j){
      bsum[j] = bi1[j*HID + u0 + ul] + bh1[j*HID + u0 + ul];
      wih[j]  = Wih1[j*HID + u0 + ul];
    }
  }
  const float bl = blin[0];
  if (j32 == 0 && tid < 512) lwl[tid] = Wlin[tid];

  // ---- prologue: h1(0) from zero state ----
  if (g == 2){
    float yv = yT[bg*16 + l15];
    float gi = bsum[0] + wih[0]*yv;
    float gg = bsum[2] + wih[2]*yv;
    float go = bsum[3] + wih[3]*yv;
    float cn = sigm(gi)*tanhf_fast(gg);
    cst = cn;
    float hn = sigm(go)*tanhf_fast(cn);
    unsigned short hb = f2bf(hn);
    unsigned e = (unsigned)(((ul>>3)*16 + l15)*8 + (ul&7));
    bnc[512 + e]       = hb;
    bnc[512 + 256 + e] = f2bf(hn - bf2f(hb));
  }
  __syncthreads();
  if (wv == 0){
    int v = lane;
    int pl = v>>5, k8l = (v>>4)&1, n = v&15;
    ushort8 val = *(const ushort8*)(bnc + 512 + v*8);
    unsigned short* dst = h1u + ((size_t)(0*8 + bg))*16384 + pl*8192 + ((j32*2 + k8l)*16 + n)*8;
    st128cc(dst, val);
    DRAIN();
    if (lane == 0) setb(flg + ((size_t)0*8 + bg)*32 + j32);
  }

  // ---- main loop: iter p consumes h2(p-1), h1(p); produces h2(p), h1(p+1), out(p-1) ----
  #pragma clang loop unroll(disable)
  for (int p = 0; p < LSEQ; ++p){
    if (wv == 11 && lane < 8) polld((unsigned*)(flg + ((size_t)p*8 + bg)*32) + lane);
    __syncthreads();                                              // B0
    {
      const unsigned short* s2 = h2u + ((size_t)(((p+3)&3)*8 + bg))*16384;
      const unsigned short* s1 = h1u + ((size_t)((p&3)*8 + bg))*16384;
      #pragma unroll
      for (int j = 0; j < 6; ++j){
        int idx = tid + j*768;
        if (idx < 4096){
          const unsigned short* src = ((idx & 2048) ? s1 : s2) + (size_t)(idx & 2047)*8;
          unsigned dstoff = ((unsigned)(idx & 2048) << 4) + (unsigned)((idx & 2047) & ~63)*16u;
          __builtin_amdgcn_global_load_lds((GU32*)src, (LU32*)(smem + dstoff), 16, 0, 0x11);
        }
      }
    }
    float yv = 0.f;
    if (g == 2){
      int ty = (p+1 < LSEQ) ? (p+1) : (LSEQ-1);
      yv = yT[ty*128 + bg*16 + l15];
    }
    __syncthreads();                                              // B1: tiles staged
    f32x4 acc = (f32x4){0.f,0.f,0.f,0.f};
    {
      const unsigned char* tb = smem + ((g==0) ? TILE2 : TILE1);
      #pragma unroll
      for (int kt = 0; kt < 16; ++kt){
        unsigned eb = (unsigned)((kt*4+hig)*16 + l15)*16u;
        short8 bhi = *(const short8*)(tb + eb);
        short8 blo = *(const short8*)(tb + 16384u + eb);
        acc = mm(whi[kt], bhi, acc);
        acc = mm(wlo[kt], bhi, acc);
        acc = mm(whi[kt], blo, acc);
      }
    }
    if (g == 1){
      *(f32x4*)(smem + PSUM + (unsigned)(mt*64 + lane)*16u) = acc;
      if (j32 == 0 && p >= 1){
        // fused out(p-1) partials from h2(p-1) tile; this wave covers k quarter mt
        float a = 0.f;
        #pragma unroll
        for (int k8r = 0; k8r < 4; ++k8r){
          int k8 = mt*16 + hig*4 + k8r;
          unsigned eb2 = (unsigned)(k8*16 + l15)*16u;
          ushort8 h8 = *(const ushort8*)(smem + TILE2 + eb2);
          ushort8 l8 = *(const ushort8*)(smem + TILE2 + 16384u + eb2);
          #pragma unroll
          for (int kk = 0; kk < 8; ++kk)
            a += (bf2f(h8[kk]) + bf2f(l8[kk])) * lwl[k8*8 + kk];
        }
        outp[(mt*4 + hig)*16 + l15] = a;
      }
    }
    __syncthreads();                                              // B2: psum/outp ready
    if (g == 0){
      f32x4 ps = *(const f32x4*)(smem + PSUM + (unsigned)(mt*64 + lane)*16u);
      float gi = acc[0] + ps[0] + bsum[0];
      float gf = acc[1] + ps[1] + bsum[1];
      float gg = acc[2] + ps[2] + bsum[2];
      float go = acc[3] + ps[3] + bsum[3];
      float cn = sigm(gf)*cst + sigm(gi)*tanhf_fast(gg);
      cst = cn;
      float hn = sigm(go)*tanhf_fast(cn);
      unsigned short hb = f2bf(hn);
      unsigned e = (unsigned)(((ul>>3)*16 + l15)*8 + (ul&7));
      bnc[e]       = hb;
      bnc[256 + e] = f2bf(hn - bf2f(hb));
    } else if (g == 2){
      float gi = acc[0] + bsum[0] + wih[0]*yv;
      float gf = acc[1] + bsum[1] + wih[1]*yv;
      float gg = acc[2] + bsum[2] + wih[2]*yv;
      float go = acc[3] + bsum[3] + wih[3]*yv;
      float cn = sigm(gf)*cst + sigm(gi)*tanhf_fast(gg);
      cst = cn;
      float hn = sigm(go)*tanhf_fast(cn);
      unsigned short hb = f2bf(hn);
      unsigned e = (unsigned)(((ul>>3)*16 + l15)*8 + (ul&7));
      bnc[512 + e]       = hb;
      bnc[512 + 256 + e] = f2bf(hn - bf2f(hb));
    }
    if (wv == 4 && j32 == 0 && p >= 1 && lane < 16){
      float s = bl;
      #pragma unroll
      for (int i = 0; i < 16; ++i) s += outp[i*16 + lane];
      out[((size_t)(bg*16 + lane))*LSEQ + (p-1)] = s;
    }
    __syncthreads();                                              // B3: bounce ready
    if (wv == 0){
      unsigned short* d2 = h2u + ((size_t)((p&3)*8 + bg))*16384;
      unsigned short* d1 = h1u + ((size_t)(((p+1)&3)*8 + bg))*16384;
      #pragma unroll
      for (int q = 0; q < 2; ++q){
        int pc = lane + q*64;
        int layer = pc >> 6, v = pc & 63;
        int pl = v>>5, k8l = (v>>4)&1, n = v&15;
        ushort8 val = *(const ushort8*)(bnc + pc*8);
        unsigned short* dst = (layer ? d1 : d2) + pl*8192 + ((j32*2 + k8l)*16 + n)*8;
        st128cc(dst, val);
      }
      DRAIN();
      if (lane == 0) setb(flg + ((size_t)(p+1)*8 + bg)*32 + j32);
    }
  }

  // ---- epilogue: out(LSEQ-1) on j32==0 blocks ----
  if (j32 == 0){
    if (wv == 11 && lane < 8) polld((unsigned*)(flg + ((size_t)LSEQ*8 + bg)*32) + lane);
    __syncthreads();
    const unsigned short* s2 = h2u + ((size_t)(3*8 + bg))*16384;   // h2(2047): slot 3
    #pragma unroll
    for (int j = 0; j < 3; ++j){
      int idx = tid + j*768;
      if (idx < 2048){
        __builtin_amdgcn_global_load_lds((GU32*)(s2 + (size_t)idx*8),
            (LU32*)(smem + (unsigned)(idx & ~63)*16u), 16, 0, 0x11);
      }
    }
    __syncthreads();
    if (g == 1){
      float a = 0.f;
      #pragma unroll
      for (int k8r = 0; k8r < 4; ++k8r){
        int k8 = mt*16 + hig*4 + k8r;
        unsigned eb2 = (unsigned)(k8*16 + l15)*16u;
        ushort8 h8 = *(const ushort8*)(smem + TILE2 + eb2);
        ushort8 l8 = *(const ushort8*)(smem + TILE2 + 16384u + eb2);
        #pragma unroll
        for (int kk = 0; kk < 8; ++kk)
          a += (bf2f(h8[kk]) + bf2f(l8[kk])) * lwl[k8*8 + kk];
      }
      outp[(mt*4 + hig)*16 + l15] = a;
    }
    __syncthreads();
    if (wv == 4 && lane < 16){
      float s = bl;
      #pragma unroll
      for (int i = 0; i < 16; ++i) s += outp[i*16 + lane];
      out[((size_t)(bg*16 + lane))*LSEQ + (LSEQ-1)] = s;
    }
  }
}

extern "C" void kernel_launch(void* const* d_in, const int* in_sizes, int n_in,
                              void* d_out, int out_size, void* d_ws, size_t ws_size,
                              hipStream_t stream){
  (void)in_sizes; (void)n_in; (void)out_size; (void)ws_size;
  const float* y    = (const float*)d_in[0];
  const float* Wih1 = (const float*)d_in[1];
  const float* Whh1 = (const float*)d_in[2];
  const float* bi1  = (const float*)d_in[3];
  const float* bh1  = (const float*)d_in[4];
  const float* Wih2 = (const float*)d_in[5];
  const float* Whh2 = (const float*)d_in[6];
  const float* bi2  = (const float*)d_in[7];
  const float* bh2  = (const float*)d_in[8];
  const float* Wlin = (const float*)d_in[9];
  const float* blin = (const float*)d_in[10];
  float* ws  = (float*)d_ws;
  float* out = (float*)d_out;

  hipLaunchKernelGGL(init_kernel, dim3(1024), dim3(256), 0, stream, y, ws);

  const float* yT = ws + OFF_YT;
  unsigned short* h1u = (unsigned short*)(ws + OFF_H1);
  unsigned short* h2u = (unsigned short*)(ws + OFF_H2);
  unsigned char* flg = (unsigned char*)(ws + OFF_FLG);

  void* args[] = { (void*)&yT, (void*)&Wih1, (void*)&Whh1, (void*)&bi1, (void*)&bh1,
                   (void*)&Wih2, (void*)&Whh2, (void*)&bi2, (void*)&bh2,
                   (void*)&Wlin, (void*)&blin, (void*)&h1u, (void*)&h2u,
                   (void*)&out, (void*)&flg };
  hipLaunchCooperativeKernel((void*)lstm_kernel, dim3(256), dim3(768), args, 0, stream);
}